// Round 8
// baseline (2407.381 us; speedup 1.0000x reference)
//
#include <hip/hip_runtime.h>

// Problem constants (match reference)
#define U_NODES 100000
#define I_NODES 50000
#define N_NODES 150000   // U + I
#define EMB_D   64
#define FEAT_K  256
#define N_LAYERS 4

typedef __attribute__((ext_vector_type(8))) short short8;
typedef __attribute__((ext_vector_type(4))) float f32x4;

// f32 -> bf16 round-to-nearest-even (bit trick)
static __device__ __forceinline__ unsigned short f2bf(float f) {
    unsigned u = __builtin_bit_cast(unsigned, f);
    u += 0x7fffu + ((u >> 16) & 1u);
    return (unsigned short)(u >> 16);
}
static __device__ __forceinline__ float bflo(unsigned u) {
    return __builtin_bit_cast(float, u << 16);
}
static __device__ __forceinline__ float bfhi(unsigned u) {
    return __builtin_bit_cast(float, u & 0xffff0000u);
}

// ---------------------------------------------------------------------------
__global__ __launch_bounds__(256) void k_count(const int* __restrict__ col,
                                               int* __restrict__ deg, int E) {
    int e = blockIdx.x * 256 + threadIdx.x;
    if (e < E) atomicAdd(&deg[col[e]], 1);
}

// dinv + degree-bucket histogram (bucket = min(deg>>2, 15))
__global__ __launch_bounds__(256) void k_dinv(const int* __restrict__ deg,
                                              float* __restrict__ dinv,
                                              int* __restrict__ bcnt, int n) {
    int i = blockIdx.x * 256 + threadIdx.x;
    if (i < n) {
        int d = deg[i];
        dinv[i] = (d > 0) ? rsqrtf((float)d) : 0.0f;
        atomicAdd(&bcnt[min(d >> 2, 15)], 1);
    }
}

__global__ __launch_bounds__(256) void k_scan_a(const int* __restrict__ deg,
                                                int* __restrict__ rs,
                                                int* __restrict__ bsum, int n) {
    __shared__ int wsum[4];
    int t = threadIdx.x;
    int i = blockIdx.x * 256 + t;
    int v = (i < n) ? deg[i] : 0;
    int x = v;
    #pragma unroll
    for (int off = 1; off < 64; off <<= 1) {
        int y = __shfl_up(x, off, 64);
        if ((t & 63) >= off) x += y;
    }
    if ((t & 63) == 63) wsum[t >> 6] = x;
    __syncthreads();
    int base = 0;
    #pragma unroll
    for (int w = 0; w < 4; ++w) base += (w < (t >> 6)) ? wsum[w] : 0;
    if (i < n) rs[i] = base + x - v;
    if (t == 255) bsum[blockIdx.x] = base + x;
}

__global__ __launch_bounds__(1024) void k_scan_b(int* __restrict__ bs, int nb) {
    __shared__ int wsum[16];
    int t = threadIdx.x;
    int v = (t < nb) ? bs[t] : 0;
    int x = v;
    #pragma unroll
    for (int off = 1; off < 64; off <<= 1) {
        int y = __shfl_up(x, off, 64);
        if ((t & 63) >= off) x += y;
    }
    if ((t & 63) == 63) wsum[t >> 6] = x;
    __syncthreads();
    int base = 0;
    #pragma unroll
    for (int w = 0; w < 16; ++w) base += (w < (t >> 6)) ? wsum[w] : 0;
    if (t < nb) bs[t] = base + x - v;
}

__global__ __launch_bounds__(256) void k_scan_c(int* __restrict__ rs,
                                                const int* __restrict__ bsum,
                                                int* __restrict__ cursor,
                                                int n, int E) {
    int i = blockIdx.x * 256 + threadIdx.x;
    if (i < n) {
        int v = rs[i] + bsum[blockIdx.x];
        rs[i] = v;
        cursor[i] = v;
    }
    if (i == 0) rs[n] = E;
}

// Exclusive scan of the 16 bucket counts -> bucket cursors (trivial size)
__global__ void k_bscan(const int* __restrict__ bcnt, int* __restrict__ bcur) {
    if (threadIdx.x == 0 && blockIdx.x == 0) {
        int acc = 0;
        for (int b = 0; b < 16; ++b) { int c = bcnt[b]; bcur[b] = acc; acc += c; }
    }
}

// Degree-bucketed node permutation: nodes with similar degree land adjacent,
// so the 8 node-groups sharing a wave have equal gather trip counts.
__global__ __launch_bounds__(256) void k_perm(const int* __restrict__ deg,
                                              int* __restrict__ bcur,
                                              int* __restrict__ perm, int n) {
    int i = blockIdx.x * 256 + threadIdx.x;
    if (i < n) {
        int b = min(deg[i] >> 2, 15);
        int pos = atomicAdd(&bcur[b], 1);
        perm[pos] = i;
    }
}

// CSR fill: ONE scattered 8B nontemporal write per edge (src, norm packed).
// nt store bypasses L2 write-allocate -> no partially-dirty line churn.
__global__ __launch_bounds__(256) void k_fill(const int* __restrict__ row,
                                              const int* __restrict__ col,
                                              const float* __restrict__ dinv,
                                              int* __restrict__ cursor,
                                              int2* __restrict__ csr, int E) {
    int e = blockIdx.x * 256 + threadIdx.x;
    if (e < E) {
        int r = row[e], c = col[e];
        int p = atomicAdd(&cursor[c], 1);
        unsigned long long v =
            ((unsigned long long)__builtin_bit_cast(unsigned, dinv[r] * dinv[c]) << 32)
            | (unsigned)r;   // little-endian: low word -> .x (src), high -> .y (nrm)
        __builtin_nontemporal_store(v, (unsigned long long*)&csr[p]);
    }
}

// Convert W matrices to bf16 (once per call; 32K elements total)
__global__ __launch_bounds__(256) void k_cvtw(const float* __restrict__ wu,
                                              const float* __restrict__ wi,
                                              unsigned short* __restrict__ wub,
                                              unsigned short* __restrict__ wib) {
    int i = blockIdx.x * 256 + threadIdx.x;
    if (i < EMB_D * FEAT_K) wub[i] = f2bf(wu[i]);
    else                    wib[i - EMB_D * FEAT_K] = f2bf(wi[i - EMB_D * FEAT_K]);
}

// Init: x0 (bf16) = concat(emb_users, emb_items). One thread per 8 elements.
__global__ __launch_bounds__(256) void k_init(const float4* __restrict__ eu,
                                              const float4* __restrict__ ei,
                                              uint4* __restrict__ x,
                                              int n8u, int n8) {
    int i = blockIdx.x * 256 + threadIdx.x;
    if (i >= n8) return;
    const float4* s = (i < n8u) ? (eu + (size_t)i * 2) : (ei + (size_t)(i - n8u) * 2);
    float4 p0 = s[0], p1 = s[1];
    uint4 r;
    r.x = (unsigned)f2bf(p0.x) | ((unsigned)f2bf(p0.y) << 16);
    r.y = (unsigned)f2bf(p0.z) | ((unsigned)f2bf(p0.w) << 16);
    r.z = (unsigned)f2bf(p1.x) | ((unsigned)f2bf(p1.y) << 16);
    r.w = (unsigned)f2bf(p1.z) | ((unsigned)f2bf(p1.w) << 16);
    x[i] = r;
}

// NOTE: macro params use trailing-underscore names (R5 lesson: never collide
// with .x/.y/.z/.w member tokens).
#define ACC8(v_, w_)                       \
    s0 = fmaf(bflo((v_).x), (w_), s0);     \
    s1 = fmaf(bfhi((v_).x), (w_), s1);     \
    s2 = fmaf(bflo((v_).y), (w_), s2);     \
    s3 = fmaf(bfhi((v_).y), (w_), s3);     \
    s4 = fmaf(bflo((v_).z), (w_), s4);     \
    s5 = fmaf(bfhi((v_).z), (w_), s5);     \
    s6 = fmaf(bflo((v_).w), (w_), s6);     \
    s7 = fmaf(bfhi((v_).w), (w_), s7);

// Masked 4-wide gather round: always 4 outstanding gathers; OOB lanes are
// clamped to the last edge with weight zeroed (wasted loads hit same line).
#define GATHER4(xsrc_, ep_, em_)                                              \
    {                                                                         \
        int i0_ = (ep_), i1_ = min((ep_) + 1, (em_));                         \
        int i2_ = min((ep_) + 2, (em_)), i3_ = min((ep_) + 3, (em_));         \
        int2 pa_ = csr[i0_], pb_ = csr[i1_], pc_ = csr[i2_], pd_ = csr[i3_];  \
        float wa_ = __builtin_bit_cast(float, pa_.y);                         \
        float wb_ = ((ep_) + 1 <= (em_)) ? __builtin_bit_cast(float, pb_.y) : 0.f; \
        float wc_ = ((ep_) + 2 <= (em_)) ? __builtin_bit_cast(float, pc_.y) : 0.f; \
        float wd_ = ((ep_) + 3 <= (em_)) ? __builtin_bit_cast(float, pd_.y) : 0.f; \
        uint4 va_ = (xsrc_)[(size_t)pa_.x * 8 + lane];                        \
        uint4 vb_ = (xsrc_)[(size_t)pb_.x * 8 + lane];                        \
        uint4 vc_ = (xsrc_)[(size_t)pc_.x * 8 + lane];                        \
        uint4 vd_ = (xsrc_)[(size_t)pd_.x * 8 + lane];                        \
        ACC8(va_, wa_) ACC8(vb_, wb_) ACC8(vc_, wc_) ACC8(vd_, wd_)           \
    }

// Pull-mode aggregation (layers 1..3), bf16 state: 8 lanes/node, 16B/lane.
// Node order comes from the degree-bucketed permutation.
__global__ __launch_bounds__(256) void k_agg(const uint4* __restrict__ xin,
                                             uint4* __restrict__ xout,
                                             const int* __restrict__ rs,
                                             const int2* __restrict__ csr,
                                             const int* __restrict__ perm,
                                             int n_nodes) {
    int idx = blockIdx.x * 256 + threadIdx.x;
    int gidx = idx >> 3;
    int lane = idx & 7;
    if (gidx >= n_nodes) return;
    int node = perm[gidx];
    int e0 = rs[node], e1 = rs[node + 1];
    float s0 = 0.f, s1 = 0.f, s2 = 0.f, s3 = 0.f;
    float s4 = 0.f, s5 = 0.f, s6 = 0.f, s7 = 0.f;
    int em = e1 - 1;
    for (int ep = e0; ep < e1; ep += 4) GATHER4(xin, ep, em)
    uint4 r;
    r.x = (unsigned)f2bf(s0) | ((unsigned)f2bf(s1) << 16);
    r.y = (unsigned)f2bf(s2) | ((unsigned)f2bf(s3) << 16);
    r.z = (unsigned)f2bf(s4) | ((unsigned)f2bf(s5) << 16);
    r.w = (unsigned)f2bf(s6) | ((unsigned)f2bf(s7) << 16);
    xout[(size_t)node * 8 + lane] = r;
}

// Layer 4 + fused sum: s = gather(x3); out_row = (emb + x1 + x2 + x3 + s)/25
__global__ __launch_bounds__(256) void k_agg4(const uint4* __restrict__ x3,
                                              const uint4* __restrict__ x1,
                                              const uint4* __restrict__ x2,
                                              const float* __restrict__ embU,
                                              const float* __restrict__ embI,
                                              float* __restrict__ outp,
                                              const int* __restrict__ rs,
                                              const int2* __restrict__ csr,
                                              const int* __restrict__ perm,
                                              int n_nodes, int U) {
    int idx = blockIdx.x * 256 + threadIdx.x;
    int gidx = idx >> 3;
    int lane = idx & 7;
    if (gidx >= n_nodes) return;
    int node = perm[gidx];
    int e0 = rs[node], e1 = rs[node + 1];
    float s0 = 0.f, s1 = 0.f, s2 = 0.f, s3 = 0.f;
    float s4 = 0.f, s5 = 0.f, s6 = 0.f, s7 = 0.f;
    int em = e1 - 1;
    for (int ep = e0; ep < e1; ep += 4) GATHER4(x3, ep, em)
    // row reads: x1,x2,x3 bf16 + emb f32
    uint4 v1 = x1[(size_t)node * 8 + lane];
    uint4 v2 = x2[(size_t)node * 8 + lane];
    uint4 v3 = x3[(size_t)node * 8 + lane];
    const float* ebp = (node < U) ? (embU + (size_t)node * EMB_D)
                                  : (embI + (size_t)(node - U) * EMB_D);
    float4 ea = ((const float4*)ebp)[lane * 2];
    float4 eb2 = ((const float4*)ebp)[lane * 2 + 1];
    const float sc = 1.0f / 25.0f;
    float4 o0, o1;
    o0.x = (ea.x  + bflo(v1.x) + bflo(v2.x) + bflo(v3.x) + s0) * sc;
    o0.y = (ea.y  + bfhi(v1.x) + bfhi(v2.x) + bfhi(v3.x) + s1) * sc;
    o0.z = (ea.z  + bflo(v1.y) + bflo(v2.y) + bflo(v3.y) + s2) * sc;
    o0.w = (ea.w  + bfhi(v1.y) + bfhi(v2.y) + bfhi(v3.y) + s3) * sc;
    o1.x = (eb2.x + bflo(v1.z) + bflo(v2.z) + bflo(v3.z) + s4) * sc;
    o1.y = (eb2.y + bfhi(v1.z) + bfhi(v2.z) + bfhi(v3.z) + s5) * sc;
    o1.z = (eb2.z + bflo(v1.w) + bflo(v2.w) + bflo(v3.w) + s6) * sc;
    o1.w = (eb2.w + bfhi(v1.w) + bfhi(v2.w) + bfhi(v3.w) + s7) * sc;
    float4* op = (float4*)(outp + (size_t)node * EMB_D) + lane * 2;
    op[0] = o0;
    op[1] = o1;
}

// ---------------------------------------------------------------------------
// Projection via MFMA bf16: out[r][c] += (F @ W^T)[r][c]   (sum/25 already in out)
// 512 threads = 8 waves/block sharing one 32 KB sB -> 4 blocks/CU = 32 waves/CU
// (occupancy cap 100%, was 62% with 256-thr blocks). Wave owns 16 rows x 64 cols;
// 16 A float4 loads issued up-front; W staged once in LDS [kk][nt][c].
// Fragment layouts (16x16x32 bf16, m89/m91-verified):
//   A: row = l&15, k = (l>>4)*8 + j ;  B: col = l&15, k = (l>>4)*8 + j
//   D: col = l&15, row = (l>>4)*4 + reg
__global__ __launch_bounds__(512) void k_projm(const float* __restrict__ FU,
                                               const float* __restrict__ FI,
                                               const unsigned short* __restrict__ WUb,
                                               const unsigned short* __restrict__ WIb,
                                               float* __restrict__ out,
                                               int nbU, int U, int I) {
    __shared__ uint4 sB[2048];   // 32 KB: [kk(32)][nt(4)][c(16)]
    const bool isU = ((int)blockIdx.x < nbU);
    const uint4* __restrict__ Wb4 = (const uint4*)(isU ? WUb : WIb);
    #pragma unroll
    for (int i = 0; i < 4; ++i) {
        int d = threadIdx.x + i * 512;          // 0..2047
        int kk = d >> 6, nt = (d >> 4) & 3, c = d & 15;
        sB[d] = Wb4[(size_t)(nt * 16 + c) * 32 + kk];
    }

    const float* __restrict__ F = isU ? FU : FI;
    float* __restrict__ o = isU ? out : out + (size_t)U * EMB_D;
    const int M = isU ? U : I;
    const int wave = threadIdx.x >> 6;           // 0..7
    const int lane = threadIdx.x & 63;
    const int l15  = lane & 15;
    const int kq   = lane >> 4;
    const int row0 = (isU ? (int)blockIdx.x : (int)blockIdx.x - nbU) * 128 + wave * 16;
    const int arow = min(row0 + l15, M - 1);     // clamp: dup rows, discarded at store
    const float* fb = F + (size_t)arow * FEAT_K + kq * 8;

    // issue ALL 16 A loads (64 VGPR) before the barrier
    float4 a0 = ((const float4*)(fb +   0))[0], a1 = ((const float4*)(fb +   0))[1];
    float4 a2 = ((const float4*)(fb +  32))[0], a3 = ((const float4*)(fb +  32))[1];
    float4 a4 = ((const float4*)(fb +  64))[0], a5 = ((const float4*)(fb +  64))[1];
    float4 a6 = ((const float4*)(fb +  96))[0], a7 = ((const float4*)(fb +  96))[1];
    float4 a8 = ((const float4*)(fb + 128))[0], a9 = ((const float4*)(fb + 128))[1];
    float4 aa = ((const float4*)(fb + 160))[0], ab = ((const float4*)(fb + 160))[1];
    float4 ac = ((const float4*)(fb + 192))[0], ad = ((const float4*)(fb + 192))[1];
    float4 ae = ((const float4*)(fb + 224))[0], af = ((const float4*)(fb + 224))[1];

    __syncthreads();

    f32x4 acc0 = {0.f, 0.f, 0.f, 0.f};
    f32x4 acc1 = {0.f, 0.f, 0.f, 0.f};
    f32x4 acc2 = {0.f, 0.f, 0.f, 0.f};
    f32x4 acc3 = {0.f, 0.f, 0.f, 0.f};

#define CVT2(d_, lo_, hi_) asm("v_cvt_pk_bf16_f32 %0, %1, %2" : "=v"(d_) : "v"(lo_), "v"(hi_))
#define KSTEP(ks_, xa_, ya_)                                                   \
    {                                                                          \
        unsigned p0, p1, p2, p3;                                               \
        CVT2(p0, (xa_).x, (xa_).y); CVT2(p1, (xa_).z, (xa_).w);                \
        CVT2(p2, (ya_).x, (ya_).y); CVT2(p3, (ya_).z, (ya_).w);                \
        uint4 up; up.x = p0; up.y = p1; up.z = p2; up.w = p3;                  \
        short8 av = __builtin_bit_cast(short8, up);                            \
        const uint4* sbk = &sB[((ks_) * 4 + kq) * 64];                         \
        short8 b0 = __builtin_bit_cast(short8, sbk[l15]);                      \
        short8 b1 = __builtin_bit_cast(short8, sbk[16 + l15]);                 \
        short8 b2 = __builtin_bit_cast(short8, sbk[32 + l15]);                 \
        short8 b3 = __builtin_bit_cast(short8, sbk[48 + l15]);                 \
        acc0 = __builtin_amdgcn_mfma_f32_16x16x32_bf16(av, b0, acc0, 0, 0, 0); \
        acc1 = __builtin_amdgcn_mfma_f32_16x16x32_bf16(av, b1, acc1, 0, 0, 0); \
        acc2 = __builtin_amdgcn_mfma_f32_16x16x32_bf16(av, b2, acc2, 0, 0, 0); \
        acc3 = __builtin_amdgcn_mfma_f32_16x16x32_bf16(av, b3, acc3, 0, 0, 0); \
    }

    KSTEP(0, a0, a1) KSTEP(1, a2, a3) KSTEP(2, a4, a5) KSTEP(3, a6, a7)
    KSTEP(4, a8, a9) KSTEP(5, aa, ab) KSTEP(6, ac, ad) KSTEP(7, ae, af)
#undef KSTEP
#undef CVT2

    #pragma unroll
    for (int r = 0; r < 4; ++r) {
        int grow = row0 + kq * 4 + r;
        if (grow < M) {
            float* op = o + (size_t)grow * EMB_D + l15;
            op[0]  += acc0[r];
            op[16] += acc1[r];
            op[32] += acc2[r];
            op[48] += acc3[r];
        }
    }
}

// ---------------------------------------------------------------------------
extern "C" void kernel_launch(void* const* d_in, const int* in_sizes, int n_in,
                              void* d_out, int out_size, void* d_ws, size_t ws_size,
                              hipStream_t stream) {
    const int E = in_sizes[0] / 2;
    const int N = N_NODES, U = U_NODES;

    const int*   edge  = (const int*)d_in[0];
    const float* emb_u = (const float*)d_in[1];
    const float* emb_i = (const float*)d_in[2];
    const float* fu    = (const float*)d_in[3];
    const float* fi    = (const float*)d_in[4];
    const float* wu    = (const float*)d_in[5];
    const float* wi    = (const float*)d_in[6];
    const int* row = edge;
    const int* col = edge + E;

    // Workspace carve (aligned 256B). ~88 MB total.
    char* p = (char*)d_ws;
    auto carve = [&](size_t bytes) -> void* {
        void* q = (void*)p;
        p += (bytes + 255) & ~(size_t)255;
        return q;
    };
    float* dinv    = (float*)carve((size_t)N * 4);
    int*   deg     = (int*)  carve((size_t)N * 4);
    int*   rs      = (int*)  carve((size_t)(N + 1) * 4);
    int*   cursor  = (int*)  carve((size_t)N * 4);
    int*   bsum    = (int*)  carve(1024 * 4);
    int*   bcnt    = (int*)  carve(32 * 4);             // [0..15] counts, [16..31] cursors
    int*   perm    = (int*)  carve((size_t)N * 4);
    int2*  csr     = (int2*) carve((size_t)E * 8);      // packed (src, norm)
    unsigned short* wub = (unsigned short*)carve((size_t)EMB_D * FEAT_K * 2);
    unsigned short* wib = (unsigned short*)carve((size_t)EMB_D * FEAT_K * 2);
    uint4* x0 = (uint4*)carve((size_t)N * EMB_D * 2);   // bf16 layer states
    uint4* x1 = (uint4*)carve((size_t)N * EMB_D * 2);
    uint4* x2 = (uint4*)carve((size_t)N * EMB_D * 2);
    uint4* x3 = (uint4*)carve((size_t)N * EMB_D * 2);
    int* bcur = bcnt + 16;

    float* outp = (float*)d_out;   // [N][64] == [u_final; i_final]

    const int NB  = (N + 255) / 256;
    const int EB  = (E + 255) / 256;
    const int XB8 = ((N * 8) + 255) / 256;

    hipMemsetAsync(deg, 0, (size_t)N * 4, stream);
    hipMemsetAsync(bcnt, 0, 32 * 4, stream);
    k_count<<<EB, 256, 0, stream>>>(col, deg, E);
    k_dinv<<<NB, 256, 0, stream>>>(deg, dinv, bcnt, N);
    k_scan_a<<<NB, 256, 0, stream>>>(deg, rs, bsum, N);
    k_scan_b<<<1, 1024, 0, stream>>>(bsum, NB);
    k_scan_c<<<NB, 256, 0, stream>>>(rs, bsum, cursor, N, E);
    k_bscan<<<1, 64, 0, stream>>>(bcnt, bcur);
    k_perm<<<NB, 256, 0, stream>>>(deg, bcur, perm, N);
    k_fill<<<EB, 256, 0, stream>>>(row, col, dinv, cursor, csr, E);
    k_cvtw<<<(2 * EMB_D * FEAT_K) / 256, 256, 0, stream>>>(wu, wi, wub, wib);
    k_init<<<XB8, 256, 0, stream>>>((const float4*)emb_u, (const float4*)emb_i,
                                    x0, U * 8, N * 8);
    // layers 1..3: pure propagation, bf16 state, degree-uniform waves
    k_agg<<<XB8, 256, 0, stream>>>(x0, x1, rs, csr, perm, N);
    k_agg<<<XB8, 256, 0, stream>>>(x1, x2, rs, csr, perm, N);
    k_agg<<<XB8, 256, 0, stream>>>(x2, x3, rs, csr, perm, N);
    // layer 4 fused with the (x0..x4) sum and 1/25 scale -> d_out
    k_agg4<<<XB8, 256, 0, stream>>>(x3, x1, x2, emb_u, emb_i, outp, rs, csr, perm, N, U);
    // projection: out += F @ W^T (user + item in one launch)
    const int nbU = (U + 127) / 128;             // 782
    const int nbI = (N - U + 127) / 128;         // 391
    k_projm<<<nbU + nbI, 512, 0, stream>>>(fu, fi, wub, wib, outp, nbU, U, N - U);
}

// Round 9
// 303.263 us; speedup vs baseline: 7.9383x; 7.9383x over previous
//
#include <hip/hip_runtime.h>

// Problem constants (match reference)
#define U_NODES 100000
#define I_NODES 50000
#define N_NODES 150000   // U + I
#define EMB_D   64
#define FEAT_K  256
#define N_LAYERS 4

typedef __attribute__((ext_vector_type(8))) short short8;
typedef __attribute__((ext_vector_type(4))) float f32x4;

// f32 -> bf16 round-to-nearest-even (bit trick)
static __device__ __forceinline__ unsigned short f2bf(float f) {
    unsigned u = __builtin_bit_cast(unsigned, f);
    u += 0x7fffu + ((u >> 16) & 1u);
    return (unsigned short)(u >> 16);
}
static __device__ __forceinline__ float bflo(unsigned u) {
    return __builtin_bit_cast(float, u << 16);
}
static __device__ __forceinline__ float bfhi(unsigned u) {
    return __builtin_bit_cast(float, u & 0xffff0000u);
}

// ---------------------------------------------------------------------------
__global__ __launch_bounds__(256) void k_count(const int* __restrict__ col,
                                               int* __restrict__ deg, int E) {
    int e = blockIdx.x * 256 + threadIdx.x;
    if (e < E) atomicAdd(&deg[col[e]], 1);
}

// dinv + per-block degree-bucket histogram (bucket = min(deg>>2, 15)).
// LDS histogram first; <=16 global atomics per block (Guideline 12 — the
// R8 version did 150K global atomics on 16 addresses = 1 ms of serialization).
__global__ __launch_bounds__(256) void k_dinv(const int* __restrict__ deg,
                                              float* __restrict__ dinv,
                                              int* __restrict__ bcnt,
                                              int* __restrict__ blockhist, int n) {
    __shared__ int h[16];
    int t = threadIdx.x;
    if (t < 16) h[t] = 0;
    __syncthreads();
    int i = blockIdx.x * 256 + t;
    if (i < n) {
        int d = deg[i];
        dinv[i] = (d > 0) ? rsqrtf((float)d) : 0.0f;
        atomicAdd(&h[min(d >> 2, 15)], 1);   // LDS atomic
    }
    __syncthreads();
    if (t < 16) {
        int c = h[t];
        blockhist[blockIdx.x * 16 + t] = c;
        if (c) atomicAdd(&bcnt[t], c);       // one global atomic per bucket per block
    }
}

__global__ __launch_bounds__(256) void k_scan_a(const int* __restrict__ deg,
                                                int* __restrict__ rs,
                                                int* __restrict__ bsum, int n) {
    __shared__ int wsum[4];
    int t = threadIdx.x;
    int i = blockIdx.x * 256 + t;
    int v = (i < n) ? deg[i] : 0;
    int x = v;
    #pragma unroll
    for (int off = 1; off < 64; off <<= 1) {
        int y = __shfl_up(x, off, 64);
        if ((t & 63) >= off) x += y;
    }
    if ((t & 63) == 63) wsum[t >> 6] = x;
    __syncthreads();
    int base = 0;
    #pragma unroll
    for (int w = 0; w < 4; ++w) base += (w < (t >> 6)) ? wsum[w] : 0;
    if (i < n) rs[i] = base + x - v;
    if (t == 255) bsum[blockIdx.x] = base + x;
}

__global__ __launch_bounds__(1024) void k_scan_b(int* __restrict__ bs, int nb) {
    __shared__ int wsum[16];
    int t = threadIdx.x;
    int v = (t < nb) ? bs[t] : 0;
    int x = v;
    #pragma unroll
    for (int off = 1; off < 64; off <<= 1) {
        int y = __shfl_up(x, off, 64);
        if ((t & 63) >= off) x += y;
    }
    if ((t & 63) == 63) wsum[t >> 6] = x;
    __syncthreads();
    int base = 0;
    #pragma unroll
    for (int w = 0; w < 16; ++w) base += (w < (t >> 6)) ? wsum[w] : 0;
    if (t < nb) bs[t] = base + x - v;
}

__global__ __launch_bounds__(256) void k_scan_c(int* __restrict__ rs,
                                                const int* __restrict__ bsum,
                                                int* __restrict__ cursor,
                                                int n, int E) {
    int i = blockIdx.x * 256 + threadIdx.x;
    if (i < n) {
        int v = rs[i] + bsum[blockIdx.x];
        rs[i] = v;
        cursor[i] = v;
    }
    if (i == 0) rs[n] = E;
}

// Exclusive scan of the 16 bucket totals -> bucket bases (trivial size)
__global__ void k_bscan(const int* __restrict__ bcnt, int* __restrict__ bbase) {
    if (threadIdx.x == 0 && blockIdx.x == 0) {
        int acc = 0;
        for (int b = 0; b < 16; ++b) { int c = bcnt[b]; bbase[b] = acc; acc += c; }
    }
}

// Per-bucket exclusive scan over per-block counts -> blockoff[block][bucket].
// 16 blocks (one per bucket) x 1 wave; 586 entries in ~10 shfl-scan rounds.
__global__ __launch_bounds__(64) void k_boff(const int* __restrict__ blockhist,
                                             const int* __restrict__ bbase,
                                             int* __restrict__ blockoff, int nb) {
    int b = blockIdx.x;
    int lane = threadIdx.x;
    int carry = bbase[b];
    for (int j0 = 0; j0 < nb; j0 += 64) {
        int j = j0 + lane;
        int v = (j < nb) ? blockhist[j * 16 + b] : 0;
        int x = v;
        #pragma unroll
        for (int off = 1; off < 64; off <<= 1) {
            int y = __shfl_up(x, off, 64);
            if (lane >= off) x += y;
        }
        if (j < nb) blockoff[j * 16 + b] = carry + x - v;
        carry += __shfl(x, 63, 64);
    }
}

// Degree-bucketed node permutation via block-local LDS cursors (no global
// atomic contention; order within a bucket is arbitrary, which is fine).
__global__ __launch_bounds__(256) void k_perm(const int* __restrict__ deg,
                                              const int* __restrict__ blockoff,
                                              int* __restrict__ perm, int n) {
    __shared__ int cur[16];
    int t = threadIdx.x;
    if (t < 16) cur[t] = blockoff[blockIdx.x * 16 + t];
    __syncthreads();
    int i = blockIdx.x * 256 + t;
    if (i < n) {
        int b = min(deg[i] >> 2, 15);
        int pos = atomicAdd(&cur[b], 1);     // LDS atomic
        perm[pos] = i;
    }
}

// CSR fill: ONE scattered 8B nontemporal write per edge (src, norm packed).
__global__ __launch_bounds__(256) void k_fill(const int* __restrict__ row,
                                              const int* __restrict__ col,
                                              const float* __restrict__ dinv,
                                              int* __restrict__ cursor,
                                              int2* __restrict__ csr, int E) {
    int e = blockIdx.x * 256 + threadIdx.x;
    if (e < E) {
        int r = row[e], c = col[e];
        int p = atomicAdd(&cursor[c], 1);
        unsigned long long v =
            ((unsigned long long)__builtin_bit_cast(unsigned, dinv[r] * dinv[c]) << 32)
            | (unsigned)r;   // low word -> .x (src), high -> .y (nrm)
        __builtin_nontemporal_store(v, (unsigned long long*)&csr[p]);
    }
}

// Convert W matrices to bf16 (once per call; 32K elements total)
__global__ __launch_bounds__(256) void k_cvtw(const float* __restrict__ wu,
                                              const float* __restrict__ wi,
                                              unsigned short* __restrict__ wub,
                                              unsigned short* __restrict__ wib) {
    int i = blockIdx.x * 256 + threadIdx.x;
    if (i < EMB_D * FEAT_K) wub[i] = f2bf(wu[i]);
    else                    wib[i - EMB_D * FEAT_K] = f2bf(wi[i - EMB_D * FEAT_K]);
}

// Init: x0 (bf16) = concat(emb_users, emb_items). One thread per 8 elements.
__global__ __launch_bounds__(256) void k_init(const float4* __restrict__ eu,
                                              const float4* __restrict__ ei,
                                              uint4* __restrict__ x,
                                              int n8u, int n8) {
    int i = blockIdx.x * 256 + threadIdx.x;
    if (i >= n8) return;
    const float4* s = (i < n8u) ? (eu + (size_t)i * 2) : (ei + (size_t)(i - n8u) * 2);
    float4 p0 = s[0], p1 = s[1];
    uint4 r;
    r.x = (unsigned)f2bf(p0.x) | ((unsigned)f2bf(p0.y) << 16);
    r.y = (unsigned)f2bf(p0.z) | ((unsigned)f2bf(p0.w) << 16);
    r.z = (unsigned)f2bf(p1.x) | ((unsigned)f2bf(p1.y) << 16);
    r.w = (unsigned)f2bf(p1.z) | ((unsigned)f2bf(p1.w) << 16);
    x[i] = r;
}

// NOTE: macro params use trailing-underscore names (R5 lesson: never collide
// with .x/.y/.z/.w member tokens).
#define ACC8(v_, w_)                       \
    s0 = fmaf(bflo((v_).x), (w_), s0);     \
    s1 = fmaf(bfhi((v_).x), (w_), s1);     \
    s2 = fmaf(bflo((v_).y), (w_), s2);     \
    s3 = fmaf(bfhi((v_).y), (w_), s3);     \
    s4 = fmaf(bflo((v_).z), (w_), s4);     \
    s5 = fmaf(bfhi((v_).z), (w_), s5);     \
    s6 = fmaf(bflo((v_).w), (w_), s6);     \
    s7 = fmaf(bfhi((v_).w), (w_), s7);

// Masked 4-wide gather round: always 4 outstanding gathers; OOB lanes are
// clamped to the last edge with weight zeroed.
#define GATHER4(xsrc_, ep_, em_)                                              \
    {                                                                         \
        int i0_ = (ep_), i1_ = min((ep_) + 1, (em_));                         \
        int i2_ = min((ep_) + 2, (em_)), i3_ = min((ep_) + 3, (em_));         \
        int2 pa_ = csr[i0_], pb_ = csr[i1_], pc_ = csr[i2_], pd_ = csr[i3_];  \
        float wa_ = __builtin_bit_cast(float, pa_.y);                         \
        float wb_ = ((ep_) + 1 <= (em_)) ? __builtin_bit_cast(float, pb_.y) : 0.f; \
        float wc_ = ((ep_) + 2 <= (em_)) ? __builtin_bit_cast(float, pc_.y) : 0.f; \
        float wd_ = ((ep_) + 3 <= (em_)) ? __builtin_bit_cast(float, pd_.y) : 0.f; \
        uint4 va_ = (xsrc_)[(size_t)pa_.x * 8 + lane];                        \
        uint4 vb_ = (xsrc_)[(size_t)pb_.x * 8 + lane];                        \
        uint4 vc_ = (xsrc_)[(size_t)pc_.x * 8 + lane];                        \
        uint4 vd_ = (xsrc_)[(size_t)pd_.x * 8 + lane];                        \
        ACC8(va_, wa_) ACC8(vb_, wb_) ACC8(vc_, wc_) ACC8(vd_, wd_)           \
    }

// Pull-mode aggregation (layers 1..3), bf16 state: 8 lanes/node, 16B/lane.
// Node order from the degree-bucketed permutation (wave-uniform trip counts).
__global__ __launch_bounds__(256) void k_agg(const uint4* __restrict__ xin,
                                             uint4* __restrict__ xout,
                                             const int* __restrict__ rs,
                                             const int2* __restrict__ csr,
                                             const int* __restrict__ perm,
                                             int n_nodes) {
    int idx = blockIdx.x * 256 + threadIdx.x;
    int gidx = idx >> 3;
    int lane = idx & 7;
    if (gidx >= n_nodes) return;
    int node = perm[gidx];
    int e0 = rs[node], e1 = rs[node + 1];
    float s0 = 0.f, s1 = 0.f, s2 = 0.f, s3 = 0.f;
    float s4 = 0.f, s5 = 0.f, s6 = 0.f, s7 = 0.f;
    int em = e1 - 1;
    for (int ep = e0; ep < e1; ep += 4) GATHER4(xin, ep, em)
    uint4 r;
    r.x = (unsigned)f2bf(s0) | ((unsigned)f2bf(s1) << 16);
    r.y = (unsigned)f2bf(s2) | ((unsigned)f2bf(s3) << 16);
    r.z = (unsigned)f2bf(s4) | ((unsigned)f2bf(s5) << 16);
    r.w = (unsigned)f2bf(s6) | ((unsigned)f2bf(s7) << 16);
    xout[(size_t)node * 8 + lane] = r;
}

// Layer 4 + fused sum: s = gather(x3); out_row = (emb + x1 + x2 + x3 + s)/25
__global__ __launch_bounds__(256) void k_agg4(const uint4* __restrict__ x3,
                                              const uint4* __restrict__ x1,
                                              const uint4* __restrict__ x2,
                                              const float* __restrict__ embU,
                                              const float* __restrict__ embI,
                                              float* __restrict__ outp,
                                              const int* __restrict__ rs,
                                              const int2* __restrict__ csr,
                                              const int* __restrict__ perm,
                                              int n_nodes, int U) {
    int idx = blockIdx.x * 256 + threadIdx.x;
    int gidx = idx >> 3;
    int lane = idx & 7;
    if (gidx >= n_nodes) return;
    int node = perm[gidx];
    int e0 = rs[node], e1 = rs[node + 1];
    float s0 = 0.f, s1 = 0.f, s2 = 0.f, s3 = 0.f;
    float s4 = 0.f, s5 = 0.f, s6 = 0.f, s7 = 0.f;
    int em = e1 - 1;
    for (int ep = e0; ep < e1; ep += 4) GATHER4(x3, ep, em)
    uint4 v1 = x1[(size_t)node * 8 + lane];
    uint4 v2 = x2[(size_t)node * 8 + lane];
    uint4 v3 = x3[(size_t)node * 8 + lane];
    const float* ebp = (node < U) ? (embU + (size_t)node * EMB_D)
                                  : (embI + (size_t)(node - U) * EMB_D);
    float4 ea = ((const float4*)ebp)[lane * 2];
    float4 eb2 = ((const float4*)ebp)[lane * 2 + 1];
    const float sc = 1.0f / 25.0f;
    float4 o0, o1;
    o0.x = (ea.x  + bflo(v1.x) + bflo(v2.x) + bflo(v3.x) + s0) * sc;
    o0.y = (ea.y  + bfhi(v1.x) + bfhi(v2.x) + bfhi(v3.x) + s1) * sc;
    o0.z = (ea.z  + bflo(v1.y) + bflo(v2.y) + bflo(v3.y) + s2) * sc;
    o0.w = (ea.w  + bfhi(v1.y) + bfhi(v2.y) + bfhi(v3.y) + s3) * sc;
    o1.x = (eb2.x + bflo(v1.z) + bflo(v2.z) + bflo(v3.z) + s4) * sc;
    o1.y = (eb2.y + bfhi(v1.z) + bfhi(v2.z) + bfhi(v3.z) + s5) * sc;
    o1.z = (eb2.z + bflo(v1.w) + bflo(v2.w) + bflo(v3.w) + s6) * sc;
    o1.w = (eb2.w + bfhi(v1.w) + bfhi(v2.w) + bfhi(v3.w) + s7) * sc;
    float4* op = (float4*)(outp + (size_t)node * EMB_D) + lane * 2;
    op[0] = o0;
    op[1] = o1;
}

// ---------------------------------------------------------------------------
// Projection via MFMA bf16: out[r][c] += (F @ W^T)[r][c]   (sum/25 already in out)
// 512 threads = 8 waves/block sharing one 32 KB sB -> 4 blocks/CU = 32 waves/CU.
// Wave owns 16 rows x 64 cols; 16 A float4 loads up-front; W in LDS [kk][nt][c].
// Fragment layouts (16x16x32 bf16, m89/m91-verified):
//   A: row = l&15, k = (l>>4)*8 + j ;  B: col = l&15, k = (l>>4)*8 + j
//   D: col = l&15, row = (l>>4)*4 + reg
__global__ __launch_bounds__(512) void k_projm(const float* __restrict__ FU,
                                               const float* __restrict__ FI,
                                               const unsigned short* __restrict__ WUb,
                                               const unsigned short* __restrict__ WIb,
                                               float* __restrict__ out,
                                               int nbU, int U, int I) {
    __shared__ uint4 sB[2048];   // 32 KB: [kk(32)][nt(4)][c(16)]
    const bool isU = ((int)blockIdx.x < nbU);
    const uint4* __restrict__ Wb4 = (const uint4*)(isU ? WUb : WIb);
    #pragma unroll
    for (int i = 0; i < 4; ++i) {
        int d = threadIdx.x + i * 512;          // 0..2047
        int kk = d >> 6, nt = (d >> 4) & 3, c = d & 15;
        sB[d] = Wb4[(size_t)(nt * 16 + c) * 32 + kk];
    }

    const float* __restrict__ F = isU ? FU : FI;
    float* __restrict__ o = isU ? out : out + (size_t)U * EMB_D;
    const int M = isU ? U : I;
    const int wave = threadIdx.x >> 6;           // 0..7
    const int lane = threadIdx.x & 63;
    const int l15  = lane & 15;
    const int kq   = lane >> 4;
    const int row0 = (isU ? (int)blockIdx.x : (int)blockIdx.x - nbU) * 128 + wave * 16;
    const int arow = min(row0 + l15, M - 1);     // clamp: dup rows, discarded at store
    const float* fb = F + (size_t)arow * FEAT_K + kq * 8;

    // issue ALL 16 A loads (64 VGPR) before the barrier
    float4 a0 = ((const float4*)(fb +   0))[0], a1 = ((const float4*)(fb +   0))[1];
    float4 a2 = ((const float4*)(fb +  32))[0], a3 = ((const float4*)(fb +  32))[1];
    float4 a4 = ((const float4*)(fb +  64))[0], a5 = ((const float4*)(fb +  64))[1];
    float4 a6 = ((const float4*)(fb +  96))[0], a7 = ((const float4*)(fb +  96))[1];
    float4 a8 = ((const float4*)(fb + 128))[0], a9 = ((const float4*)(fb + 128))[1];
    float4 aa = ((const float4*)(fb + 160))[0], ab = ((const float4*)(fb + 160))[1];
    float4 ac = ((const float4*)(fb + 192))[0], ad = ((const float4*)(fb + 192))[1];
    float4 ae = ((const float4*)(fb + 224))[0], af = ((const float4*)(fb + 224))[1];

    __syncthreads();

    f32x4 acc0 = {0.f, 0.f, 0.f, 0.f};
    f32x4 acc1 = {0.f, 0.f, 0.f, 0.f};
    f32x4 acc2 = {0.f, 0.f, 0.f, 0.f};
    f32x4 acc3 = {0.f, 0.f, 0.f, 0.f};

#define CVT2(d_, lo_, hi_) asm("v_cvt_pk_bf16_f32 %0, %1, %2" : "=v"(d_) : "v"(lo_), "v"(hi_))
#define KSTEP(ks_, xa_, ya_)                                                   \
    {                                                                          \
        unsigned p0, p1, p2, p3;                                               \
        CVT2(p0, (xa_).x, (xa_).y); CVT2(p1, (xa_).z, (xa_).w);                \
        CVT2(p2, (ya_).x, (ya_).y); CVT2(p3, (ya_).z, (ya_).w);                \
        uint4 up; up.x = p0; up.y = p1; up.z = p2; up.w = p3;                  \
        short8 av = __builtin_bit_cast(short8, up);                            \
        const uint4* sbk = &sB[((ks_) * 4 + kq) * 64];                         \
        short8 b0 = __builtin_bit_cast(short8, sbk[l15]);                      \
        short8 b1 = __builtin_bit_cast(short8, sbk[16 + l15]);                 \
        short8 b2 = __builtin_bit_cast(short8, sbk[32 + l15]);                 \
        short8 b3 = __builtin_bit_cast(short8, sbk[48 + l15]);                 \
        acc0 = __builtin_amdgcn_mfma_f32_16x16x32_bf16(av, b0, acc0, 0, 0, 0); \
        acc1 = __builtin_amdgcn_mfma_f32_16x16x32_bf16(av, b1, acc1, 0, 0, 0); \
        acc2 = __builtin_amdgcn_mfma_f32_16x16x32_bf16(av, b2, acc2, 0, 0, 0); \
        acc3 = __builtin_amdgcn_mfma_f32_16x16x32_bf16(av, b3, acc3, 0, 0, 0); \
    }

    KSTEP(0, a0, a1) KSTEP(1, a2, a3) KSTEP(2, a4, a5) KSTEP(3, a6, a7)
    KSTEP(4, a8, a9) KSTEP(5, aa, ab) KSTEP(6, ac, ad) KSTEP(7, ae, af)
#undef KSTEP
#undef CVT2

    #pragma unroll
    for (int r = 0; r < 4; ++r) {
        int grow = row0 + kq * 4 + r;
        if (grow < M) {
            float* op = o + (size_t)grow * EMB_D + l15;
            op[0]  += acc0[r];
            op[16] += acc1[r];
            op[32] += acc2[r];
            op[48] += acc3[r];
        }
    }
}

// ---------------------------------------------------------------------------
extern "C" void kernel_launch(void* const* d_in, const int* in_sizes, int n_in,
                              void* d_out, int out_size, void* d_ws, size_t ws_size,
                              hipStream_t stream) {
    const int E = in_sizes[0] / 2;
    const int N = N_NODES, U = U_NODES;

    const int*   edge  = (const int*)d_in[0];
    const float* emb_u = (const float*)d_in[1];
    const float* emb_i = (const float*)d_in[2];
    const float* fu    = (const float*)d_in[3];
    const float* fi    = (const float*)d_in[4];
    const float* wu    = (const float*)d_in[5];
    const float* wi    = (const float*)d_in[6];
    const int* row = edge;
    const int* col = edge + E;

    const int NB  = (N + 255) / 256;
    const int EB  = (E + 255) / 256;
    const int XB8 = ((N * 8) + 255) / 256;

    // Workspace carve (aligned 256B). ~88 MB total.
    char* p = (char*)d_ws;
    auto carve = [&](size_t bytes) -> void* {
        void* q = (void*)p;
        p += (bytes + 255) & ~(size_t)255;
        return q;
    };
    float* dinv      = (float*)carve((size_t)N * 4);
    int*   deg       = (int*)  carve((size_t)N * 4);
    int*   rs        = (int*)  carve((size_t)(N + 1) * 4);
    int*   cursor    = (int*)  carve((size_t)N * 4);
    int*   bsum      = (int*)  carve(1024 * 4);
    int*   bcnt      = (int*)  carve(32 * 4);           // [0..15] totals, [16..31] bases
    int*   blockhist = (int*)  carve((size_t)NB * 16 * 4);
    int*   blockoff  = (int*)  carve((size_t)NB * 16 * 4);
    int*   perm      = (int*)  carve((size_t)N * 4);
    int2*  csr       = (int2*) carve((size_t)E * 8);    // packed (src, norm)
    unsigned short* wub = (unsigned short*)carve((size_t)EMB_D * FEAT_K * 2);
    unsigned short* wib = (unsigned short*)carve((size_t)EMB_D * FEAT_K * 2);
    uint4* x0 = (uint4*)carve((size_t)N * EMB_D * 2);   // bf16 layer states
    uint4* x1 = (uint4*)carve((size_t)N * EMB_D * 2);
    uint4* x2 = (uint4*)carve((size_t)N * EMB_D * 2);
    uint4* x3 = (uint4*)carve((size_t)N * EMB_D * 2);
    int* bbase = bcnt + 16;

    float* outp = (float*)d_out;   // [N][64] == [u_final; i_final]

    hipMemsetAsync(deg, 0, (size_t)N * 4, stream);
    hipMemsetAsync(bcnt, 0, 32 * 4, stream);
    k_count<<<EB, 256, 0, stream>>>(col, deg, E);
    k_dinv<<<NB, 256, 0, stream>>>(deg, dinv, bcnt, blockhist, N);
    k_scan_a<<<NB, 256, 0, stream>>>(deg, rs, bsum, N);
    k_scan_b<<<1, 1024, 0, stream>>>(bsum, NB);
    k_scan_c<<<NB, 256, 0, stream>>>(rs, bsum, cursor, N, E);
    k_bscan<<<1, 64, 0, stream>>>(bcnt, bbase);
    k_boff<<<16, 64, 0, stream>>>(blockhist, bbase, blockoff, NB);
    k_perm<<<NB, 256, 0, stream>>>(deg, blockoff, perm, N);
    k_fill<<<EB, 256, 0, stream>>>(row, col, dinv, cursor, csr, E);
    k_cvtw<<<(2 * EMB_D * FEAT_K) / 256, 256, 0, stream>>>(wu, wi, wub, wib);
    k_init<<<XB8, 256, 0, stream>>>((const float4*)emb_u, (const float4*)emb_i,
                                    x0, U * 8, N * 8);
    // layers 1..3: pure propagation, bf16 state, degree-uniform waves
    k_agg<<<XB8, 256, 0, stream>>>(x0, x1, rs, csr, perm, N);
    k_agg<<<XB8, 256, 0, stream>>>(x1, x2, rs, csr, perm, N);
    k_agg<<<XB8, 256, 0, stream>>>(x2, x3, rs, csr, perm, N);
    // layer 4 fused with the (x0..x4) sum and 1/25 scale -> d_out
    k_agg4<<<XB8, 256, 0, stream>>>(x3, x1, x2, emb_u, emb_i, outp, rs, csr, perm, N, U);
    // projection: out += F @ W^T (user + item in one launch)
    const int nbU = (U + 127) / 128;             // 782
    const int nbI = (N - U + 127) / 128;         // 391
    k_projm<<<nbU + nbI, 512, 0, stream>>>(fu, fi, wub, wib, outp, nbU, U, N - U);
}

// Round 10
// 276.062 us; speedup vs baseline: 8.7204x; 1.0985x over previous
//
#include <hip/hip_runtime.h>

// Problem constants (match reference)
#define U_NODES 100000
#define I_NODES 50000
#define N_NODES 150000   // U + I
#define EMB_D   64
#define FEAT_K  256
#define N_LAYERS 4

typedef __attribute__((ext_vector_type(8))) short short8;
typedef __attribute__((ext_vector_type(4))) float f32x4;

// f32 -> bf16 round-to-nearest-even (bit trick)
static __device__ __forceinline__ unsigned short f2bf(float f) {
    unsigned u = __builtin_bit_cast(unsigned, f);
    u += 0x7fffu + ((u >> 16) & 1u);
    return (unsigned short)(u >> 16);
}
static __device__ __forceinline__ float bflo(unsigned u) {
    return __builtin_bit_cast(float, u << 16);
}
static __device__ __forceinline__ float bfhi(unsigned u) {
    return __builtin_bit_cast(float, u & 0xffff0000u);
}

// ---------------------------------------------------------------------------
__global__ __launch_bounds__(256) void k_count(const int* __restrict__ col,
                                               int* __restrict__ deg, int E) {
    int e = blockIdx.x * 256 + threadIdx.x;
    if (e < E) atomicAdd(&deg[col[e]], 1);
}

__global__ __launch_bounds__(256) void k_dinv(const int* __restrict__ deg,
                                              float* __restrict__ dinv, int n) {
    int i = blockIdx.x * 256 + threadIdx.x;
    if (i < n) {
        int d = deg[i];
        dinv[i] = (d > 0) ? rsqrtf((float)d) : 0.0f;
    }
}

__global__ __launch_bounds__(256) void k_scan_a(const int* __restrict__ deg,
                                                int* __restrict__ rs,
                                                int* __restrict__ bsum, int n) {
    __shared__ int wsum[4];
    int t = threadIdx.x;
    int i = blockIdx.x * 256 + t;
    int v = (i < n) ? deg[i] : 0;
    int x = v;
    #pragma unroll
    for (int off = 1; off < 64; off <<= 1) {
        int y = __shfl_up(x, off, 64);
        if ((t & 63) >= off) x += y;
    }
    if ((t & 63) == 63) wsum[t >> 6] = x;
    __syncthreads();
    int base = 0;
    #pragma unroll
    for (int w = 0; w < 4; ++w) base += (w < (t >> 6)) ? wsum[w] : 0;
    if (i < n) rs[i] = base + x - v;
    if (t == 255) bsum[blockIdx.x] = base + x;
}

__global__ __launch_bounds__(1024) void k_scan_b(int* __restrict__ bs, int nb) {
    __shared__ int wsum[16];
    int t = threadIdx.x;
    int v = (t < nb) ? bs[t] : 0;
    int x = v;
    #pragma unroll
    for (int off = 1; off < 64; off <<= 1) {
        int y = __shfl_up(x, off, 64);
        if ((t & 63) >= off) x += y;
    }
    if ((t & 63) == 63) wsum[t >> 6] = x;
    __syncthreads();
    int base = 0;
    #pragma unroll
    for (int w = 0; w < 16; ++w) base += (w < (t >> 6)) ? wsum[w] : 0;
    if (t < nb) bs[t] = base + x - v;
}

__global__ __launch_bounds__(256) void k_scan_c(int* __restrict__ rs,
                                                const int* __restrict__ bsum,
                                                int* __restrict__ cursor,
                                                int n, int E) {
    int i = blockIdx.x * 256 + threadIdx.x;
    if (i < n) {
        int v = rs[i] + bsum[blockIdx.x];
        rs[i] = v;
        cursor[i] = v;
    }
    if (i == 0) rs[n] = E;
}

// CSR fill: ONE scattered 8B nontemporal write per edge (src, norm packed).
__global__ __launch_bounds__(256) void k_fill(const int* __restrict__ row,
                                              const int* __restrict__ col,
                                              const float* __restrict__ dinv,
                                              int* __restrict__ cursor,
                                              int2* __restrict__ csr, int E) {
    int e = blockIdx.x * 256 + threadIdx.x;
    if (e < E) {
        int r = row[e], c = col[e];
        int p = atomicAdd(&cursor[c], 1);
        unsigned long long v =
            ((unsigned long long)__builtin_bit_cast(unsigned, dinv[r] * dinv[c]) << 32)
            | (unsigned)r;   // low word -> .x (src), high -> .y (nrm)
        __builtin_nontemporal_store(v, (unsigned long long*)&csr[p]);
    }
}

// Convert W matrices to bf16 (once per call; 32K elements total)
__global__ __launch_bounds__(256) void k_cvtw(const float* __restrict__ wu,
                                              const float* __restrict__ wi,
                                              unsigned short* __restrict__ wub,
                                              unsigned short* __restrict__ wib) {
    int i = blockIdx.x * 256 + threadIdx.x;
    if (i < EMB_D * FEAT_K) wub[i] = f2bf(wu[i]);
    else                    wib[i - EMB_D * FEAT_K] = f2bf(wi[i - EMB_D * FEAT_K]);
}

// Init: x0 (bf16) = concat(emb_users, emb_items). One thread per 8 elements.
__global__ __launch_bounds__(256) void k_init(const float4* __restrict__ eu,
                                              const float4* __restrict__ ei,
                                              uint4* __restrict__ x,
                                              int n8u, int n8) {
    int i = blockIdx.x * 256 + threadIdx.x;
    if (i >= n8) return;
    const float4* s = (i < n8u) ? (eu + (size_t)i * 2) : (ei + (size_t)(i - n8u) * 2);
    float4 p0 = s[0], p1 = s[1];
    uint4 r;
    r.x = (unsigned)f2bf(p0.x) | ((unsigned)f2bf(p0.y) << 16);
    r.y = (unsigned)f2bf(p0.z) | ((unsigned)f2bf(p0.w) << 16);
    r.z = (unsigned)f2bf(p1.x) | ((unsigned)f2bf(p1.y) << 16);
    r.w = (unsigned)f2bf(p1.z) | ((unsigned)f2bf(p1.w) << 16);
    x[i] = r;
}

// NOTE: macro params use trailing-underscore names (R5 lesson: never collide
// with .x/.y/.z/.w member tokens).
#define ACC8(v_, w_)                       \
    s0 = fmaf(bflo((v_).x), (w_), s0);     \
    s1 = fmaf(bfhi((v_).x), (w_), s1);     \
    s2 = fmaf(bflo((v_).y), (w_), s2);     \
    s3 = fmaf(bfhi((v_).y), (w_), s3);     \
    s4 = fmaf(bflo((v_).z), (w_), s4);     \
    s5 = fmaf(bfhi((v_).z), (w_), s5);     \
    s6 = fmaf(bflo((v_).w), (w_), s6);     \
    s7 = fmaf(bfhi((v_).w), (w_), s7);

// Masked 4-wide gather round: always 4 outstanding gathers; OOB lanes are
// clamped to the last edge with weight zeroed.
#define GATHER4(xsrc_, ep_, em_)                                              \
    {                                                                         \
        int i0_ = (ep_), i1_ = min((ep_) + 1, (em_));                         \
        int i2_ = min((ep_) + 2, (em_)), i3_ = min((ep_) + 3, (em_));         \
        int2 pa_ = csr[i0_], pb_ = csr[i1_], pc_ = csr[i2_], pd_ = csr[i3_];  \
        float wa_ = __builtin_bit_cast(float, pa_.y);                         \
        float wb_ = ((ep_) + 1 <= (em_)) ? __builtin_bit_cast(float, pb_.y) : 0.f; \
        float wc_ = ((ep_) + 2 <= (em_)) ? __builtin_bit_cast(float, pc_.y) : 0.f; \
        float wd_ = ((ep_) + 3 <= (em_)) ? __builtin_bit_cast(float, pd_.y) : 0.f; \
        uint4 va_ = (xsrc_)[(size_t)pa_.x * 8 + lane];                        \
        uint4 vb_ = (xsrc_)[(size_t)pb_.x * 8 + lane];                        \
        uint4 vc_ = (xsrc_)[(size_t)pc_.x * 8 + lane];                        \
        uint4 vd_ = (xsrc_)[(size_t)pd_.x * 8 + lane];                        \
        ACC8(va_, wa_) ACC8(vb_, wb_) ACC8(vc_, wc_) ACC8(vd_, wd_)           \
    }

// Pull-mode aggregation (layers 1..3), bf16 state: 8 lanes/node, 16B/lane.
__global__ __launch_bounds__(256) void k_agg(const uint4* __restrict__ xin,
                                             uint4* __restrict__ xout,
                                             const int* __restrict__ rs,
                                             const int2* __restrict__ csr,
                                             int n_nodes) {
    int idx = blockIdx.x * 256 + threadIdx.x;
    int node = idx >> 3;
    int lane = idx & 7;
    if (node >= n_nodes) return;
    int e0 = rs[node], e1 = rs[node + 1];
    float s0 = 0.f, s1 = 0.f, s2 = 0.f, s3 = 0.f;
    float s4 = 0.f, s5 = 0.f, s6 = 0.f, s7 = 0.f;
    int em = e1 - 1;
    for (int ep = e0; ep < e1; ep += 4) GATHER4(xin, ep, em)
    uint4 r;
    r.x = (unsigned)f2bf(s0) | ((unsigned)f2bf(s1) << 16);
    r.y = (unsigned)f2bf(s2) | ((unsigned)f2bf(s3) << 16);
    r.z = (unsigned)f2bf(s4) | ((unsigned)f2bf(s5) << 16);
    r.w = (unsigned)f2bf(s6) | ((unsigned)f2bf(s7) << 16);
    xout[(size_t)node * 8 + lane] = r;
}

// Layer 4 + fused sum: s = gather(x3); out_row = (emb + x1 + x2 + x3 + s)/25
__global__ __launch_bounds__(256) void k_agg4(const uint4* __restrict__ x3,
                                              const uint4* __restrict__ x1,
                                              const uint4* __restrict__ x2,
                                              const float* __restrict__ embU,
                                              const float* __restrict__ embI,
                                              float* __restrict__ outp,
                                              const int* __restrict__ rs,
                                              const int2* __restrict__ csr,
                                              int n_nodes, int U) {
    int idx = blockIdx.x * 256 + threadIdx.x;
    int node = idx >> 3;
    int lane = idx & 7;
    if (node >= n_nodes) return;
    int e0 = rs[node], e1 = rs[node + 1];
    float s0 = 0.f, s1 = 0.f, s2 = 0.f, s3 = 0.f;
    float s4 = 0.f, s5 = 0.f, s6 = 0.f, s7 = 0.f;
    int em = e1 - 1;
    for (int ep = e0; ep < e1; ep += 4) GATHER4(x3, ep, em)
    uint4 v1 = x1[(size_t)node * 8 + lane];
    uint4 v2 = x2[(size_t)node * 8 + lane];
    uint4 v3 = x3[(size_t)node * 8 + lane];
    const float* ebp = (node < U) ? (embU + (size_t)node * EMB_D)
                                  : (embI + (size_t)(node - U) * EMB_D);
    float4 ea = ((const float4*)ebp)[lane * 2];
    float4 eb2 = ((const float4*)ebp)[lane * 2 + 1];
    const float sc = 1.0f / 25.0f;
    float4 o0, o1;
    o0.x = (ea.x  + bflo(v1.x) + bflo(v2.x) + bflo(v3.x) + s0) * sc;
    o0.y = (ea.y  + bfhi(v1.x) + bfhi(v2.x) + bfhi(v3.x) + s1) * sc;
    o0.z = (ea.z  + bflo(v1.y) + bflo(v2.y) + bflo(v3.y) + s2) * sc;
    o0.w = (ea.w  + bfhi(v1.y) + bfhi(v2.y) + bfhi(v3.y) + s3) * sc;
    o1.x = (eb2.x + bflo(v1.z) + bflo(v2.z) + bflo(v3.z) + s4) * sc;
    o1.y = (eb2.y + bfhi(v1.z) + bfhi(v2.z) + bfhi(v3.z) + s5) * sc;
    o1.z = (eb2.z + bflo(v1.w) + bflo(v2.w) + bflo(v3.w) + s6) * sc;
    o1.w = (eb2.w + bfhi(v1.w) + bfhi(v2.w) + bfhi(v3.w) + s7) * sc;
    float4* op = (float4*)(outp + (size_t)node * EMB_D) + lane * 2;
    op[0] = o0;
    op[1] = o1;
}

// ---------------------------------------------------------------------------
// Projection via MFMA bf16: out[r][c] += (F @ W^T)[r][c]   (sum/25 already in out)
// 256 threads = 4 waves/block; wave owns 16 rows x 64 cols; all 16 A float4
// loads issued up-front AND pinned live via empty-asm keep-alives (R9's
// VGPR_Count=48 proved the compiler sank the loads to their uses -> only ~2-4
// outstanding -> 2.1 TB/s latency-bound). W staged once in LDS [kk][nt][c].
// Fragment layouts (16x16x32 bf16, m89/m91-verified):
//   A: row = l&15, k = (l>>4)*8 + j ;  B: col = l&15, k = (l>>4)*8 + j
//   D: col = l&15, row = (l>>4)*4 + reg
#define KEEP4(v_) asm volatile("" : "+v"((v_).x), "+v"((v_).y), "+v"((v_).z), "+v"((v_).w))

__global__ __launch_bounds__(256) void k_projm(const float* __restrict__ FU,
                                               const float* __restrict__ FI,
                                               const unsigned short* __restrict__ WUb,
                                               const unsigned short* __restrict__ WIb,
                                               float* __restrict__ out,
                                               int nbU, int U, int I) {
    __shared__ uint4 sB[2048];   // 32 KB: [kk(32)][nt(4)][c(16)]
    const bool isU = ((int)blockIdx.x < nbU);
    const uint4* __restrict__ Wb4 = (const uint4*)(isU ? WUb : WIb);
    #pragma unroll
    for (int i = 0; i < 8; ++i) {
        int d = threadIdx.x + i * 256;          // 0..2047
        int kk = d >> 6, nt = (d >> 4) & 3, c = d & 15;
        sB[d] = Wb4[(size_t)(nt * 16 + c) * 32 + kk];
    }

    const float* __restrict__ F = isU ? FU : FI;
    float* __restrict__ o = isU ? out : out + (size_t)U * EMB_D;
    const int M = isU ? U : I;
    const int wave = threadIdx.x >> 6;           // 0..3
    const int lane = threadIdx.x & 63;
    const int l15  = lane & 15;
    const int kq   = lane >> 4;
    const int row0 = (isU ? (int)blockIdx.x : (int)blockIdx.x - nbU) * 64 + wave * 16;
    const int arow = min(row0 + l15, M - 1);     // clamp: dup rows, discarded at store
    const float* fb = F + (size_t)arow * FEAT_K + kq * 8;

    // issue ALL 16 A loads; keep-alives force them to materialize here
    float4 a0 = ((const float4*)(fb +   0))[0], a1 = ((const float4*)(fb +   0))[1];
    float4 a2 = ((const float4*)(fb +  32))[0], a3 = ((const float4*)(fb +  32))[1];
    float4 a4 = ((const float4*)(fb +  64))[0], a5 = ((const float4*)(fb +  64))[1];
    float4 a6 = ((const float4*)(fb +  96))[0], a7 = ((const float4*)(fb +  96))[1];
    float4 a8 = ((const float4*)(fb + 128))[0], a9 = ((const float4*)(fb + 128))[1];
    float4 aa = ((const float4*)(fb + 160))[0], ab = ((const float4*)(fb + 160))[1];
    float4 ac = ((const float4*)(fb + 192))[0], ad = ((const float4*)(fb + 192))[1];
    float4 ae = ((const float4*)(fb + 224))[0], af = ((const float4*)(fb + 224))[1];
    KEEP4(a0); KEEP4(a1); KEEP4(a2); KEEP4(a3);
    KEEP4(a4); KEEP4(a5); KEEP4(a6); KEEP4(a7);
    KEEP4(a8); KEEP4(a9); KEEP4(aa); KEEP4(ab);
    KEEP4(ac); KEEP4(ad); KEEP4(ae); KEEP4(af);

    __syncthreads();

    f32x4 acc0 = {0.f, 0.f, 0.f, 0.f};
    f32x4 acc1 = {0.f, 0.f, 0.f, 0.f};
    f32x4 acc2 = {0.f, 0.f, 0.f, 0.f};
    f32x4 acc3 = {0.f, 0.f, 0.f, 0.f};

#define CVT2(d_, lo_, hi_) asm("v_cvt_pk_bf16_f32 %0, %1, %2" : "=v"(d_) : "v"(lo_), "v"(hi_))
#define KSTEP(ks_, xa_, ya_)                                                   \
    {                                                                          \
        unsigned p0, p1, p2, p3;                                               \
        CVT2(p0, (xa_).x, (xa_).y); CVT2(p1, (xa_).z, (xa_).w);                \
        CVT2(p2, (ya_).x, (ya_).y); CVT2(p3, (ya_).z, (ya_).w);                \
        uint4 up; up.x = p0; up.y = p1; up.z = p2; up.w = p3;                  \
        short8 av = __builtin_bit_cast(short8, up);                            \
        const uint4* sbk = &sB[((ks_) * 4 + kq) * 64];                         \
        short8 b0 = __builtin_bit_cast(short8, sbk[l15]);                      \
        short8 b1 = __builtin_bit_cast(short8, sbk[16 + l15]);                 \
        short8 b2 = __builtin_bit_cast(short8, sbk[32 + l15]);                 \
        short8 b3 = __builtin_bit_cast(short8, sbk[48 + l15]);                 \
        acc0 = __builtin_amdgcn_mfma_f32_16x16x32_bf16(av, b0, acc0, 0, 0, 0); \
        acc1 = __builtin_amdgcn_mfma_f32_16x16x32_bf16(av, b1, acc1, 0, 0, 0); \
        acc2 = __builtin_amdgcn_mfma_f32_16x16x32_bf16(av, b2, acc2, 0, 0, 0); \
        acc3 = __builtin_amdgcn_mfma_f32_16x16x32_bf16(av, b3, acc3, 0, 0, 0); \
    }

    KSTEP(0, a0, a1) KSTEP(1, a2, a3) KSTEP(2, a4, a5) KSTEP(3, a6, a7)
    KSTEP(4, a8, a9) KSTEP(5, aa, ab) KSTEP(6, ac, ad) KSTEP(7, ae, af)
#undef KSTEP
#undef CVT2

    #pragma unroll
    for (int r = 0; r < 4; ++r) {
        int grow = row0 + kq * 4 + r;
        if (grow < M) {
            float* op = o + (size_t)grow * EMB_D + l15;
            op[0]  += acc0[r];
            op[16] += acc1[r];
            op[32] += acc2[r];
            op[48] += acc3[r];
        }
    }
}

// ---------------------------------------------------------------------------
extern "C" void kernel_launch(void* const* d_in, const int* in_sizes, int n_in,
                              void* d_out, int out_size, void* d_ws, size_t ws_size,
                              hipStream_t stream) {
    const int E = in_sizes[0] / 2;
    const int N = N_NODES, U = U_NODES;

    const int*   edge  = (const int*)d_in[0];
    const float* emb_u = (const float*)d_in[1];
    const float* emb_i = (const float*)d_in[2];
    const float* fu    = (const float*)d_in[3];
    const float* fi    = (const float*)d_in[4];
    const float* wu    = (const float*)d_in[5];
    const float* wi    = (const float*)d_in[6];
    const int* row = edge;
    const int* col = edge + E;

    const int NB  = (N + 255) / 256;
    const int EB  = (E + 255) / 256;
    const int XB8 = ((N * 8) + 255) / 256;

    // Workspace carve (aligned 256B). ~88 MB total.
    char* p = (char*)d_ws;
    auto carve = [&](size_t bytes) -> void* {
        void* q = (void*)p;
        p += (bytes + 255) & ~(size_t)255;
        return q;
    };
    float* dinv    = (float*)carve((size_t)N * 4);
    int*   deg     = (int*)  carve((size_t)N * 4);
    int*   rs      = (int*)  carve((size_t)(N + 1) * 4);
    int*   cursor  = (int*)  carve((size_t)N * 4);
    int*   bsum    = (int*)  carve(1024 * 4);
    int2*  csr     = (int2*) carve((size_t)E * 8);      // packed (src, norm)
    unsigned short* wub = (unsigned short*)carve((size_t)EMB_D * FEAT_K * 2);
    unsigned short* wib = (unsigned short*)carve((size_t)EMB_D * FEAT_K * 2);
    uint4* x0 = (uint4*)carve((size_t)N * EMB_D * 2);   // bf16 layer states
    uint4* x1 = (uint4*)carve((size_t)N * EMB_D * 2);
    uint4* x2 = (uint4*)carve((size_t)N * EMB_D * 2);
    uint4* x3 = (uint4*)carve((size_t)N * EMB_D * 2);

    float* outp = (float*)d_out;   // [N][64] == [u_final; i_final]

    hipMemsetAsync(deg, 0, (size_t)N * 4, stream);
    k_count<<<EB, 256, 0, stream>>>(col, deg, E);
    k_dinv<<<NB, 256, 0, stream>>>(deg, dinv, N);
    k_scan_a<<<NB, 256, 0, stream>>>(deg, rs, bsum, N);
    k_scan_b<<<1, 1024, 0, stream>>>(bsum, NB);
    k_scan_c<<<NB, 256, 0, stream>>>(rs, bsum, cursor, N, E);
    k_fill<<<EB, 256, 0, stream>>>(row, col, dinv, cursor, csr, E);
    k_cvtw<<<(2 * EMB_D * FEAT_K) / 256, 256, 0, stream>>>(wu, wi, wub, wib);
    k_init<<<XB8, 256, 0, stream>>>((const float4*)emb_u, (const float4*)emb_i,
                                    x0, U * 8, N * 8);
    // layers 1..3: pure propagation, bf16 state
    k_agg<<<XB8, 256, 0, stream>>>(x0, x1, rs, csr, N);
    k_agg<<<XB8, 256, 0, stream>>>(x1, x2, rs, csr, N);
    k_agg<<<XB8, 256, 0, stream>>>(x2, x3, rs, csr, N);
    // layer 4 fused with the (x0..x4) sum and 1/25 scale -> d_out
    k_agg4<<<XB8, 256, 0, stream>>>(x3, x1, x2, emb_u, emb_i, outp, rs, csr, N, U);
    // projection: out += F @ W^T (user + item in one launch)
    const int nbU = (U + 63) / 64;               // 1563
    const int nbI = (N - U + 63) / 64;           // 782
    k_projm<<<nbU + nbI, 256, 0, stream>>>(fu, fi, wub, wib, outp, nbU, U, N - U);
}